// Round 1
// baseline (1711.440 us; speedup 1.0000x reference)
//
#include <hip/hip_runtime.h>
#include <hip/hip_bf16.h>
#include <math.h>

// Problem constants (B=32, H=W=56, C=256, heads=8, hd=32, ws=7)
#define BATCH 32
#define HH 56
#define WW_ 56
#define NTOK 3136            // 56*56
#define C_ 256
#define HEADS_ 8
#define HD 32
#define WS_ 7
#define L_ 49
#define NWIN 2048            // 32 * 8 * 8
#define M_ 100352            // NWIN * 49  == BATCH*NTOK
#define MLPH 512

// ---------------------------------------------------------------------------
// LayerNorm kernel: one wave (64 lanes) per token, 4 floats per lane.
// WINDOWED=1: write rows in window-partitioned order (for LN1 -> QKV GEMM).
// WINDOWED=0: plain row order (LN2).
// ---------------------------------------------------------------------------
template <int WINDOWED>
__global__ __launch_bounds__(256) void ln_kernel(
    const float* __restrict__ x, const float* __restrict__ gamma,
    const float* __restrict__ beta, float* __restrict__ out)
{
    int wave = threadIdx.x >> 6;
    int lane = threadIdx.x & 63;
    int p = blockIdx.x * 4 + wave;              // token id, grid sized exactly
    const float* row = x + (size_t)p * C_;
    float4 v = *(const float4*)(row + lane * 4);
    float s  = v.x + v.y + v.z + v.w;
    float ss = v.x * v.x + v.y * v.y + v.z * v.z + v.w * v.w;
    #pragma unroll
    for (int m = 1; m < 64; m <<= 1) {
        s  += __shfl_xor(s, m, 64);
        ss += __shfl_xor(ss, m, 64);
    }
    float mean = s * (1.0f / C_);
    float var  = ss * (1.0f / C_) - mean * mean;
    float inv  = rsqrtf(var + 1e-5f);
    float4 gv = *(const float4*)(gamma + lane * 4);
    float4 bv = *(const float4*)(beta + lane * 4);
    float4 o;
    o.x = (v.x - mean) * inv * gv.x + bv.x;
    o.y = (v.y - mean) * inv * gv.y + bv.y;
    o.z = (v.z - mean) * inv * gv.z + bv.z;
    o.w = (v.w - mean) * inv * gv.w + bv.w;
    size_t orow;
    if (WINDOWED) {
        int b_ = p / NTOK, n = p % NTOK;
        int y = n / WW_, xc = n % WW_;
        int win = (b_ * 8 + y / WS_) * 8 + xc / WS_;
        int l   = (y % WS_) * WS_ + (xc % WS_);
        orow = (size_t)(win * L_ + l) * C_;
    } else {
        orow = (size_t)p * C_;
    }
    *(float4*)(out + orow + lane * 4) = o;
}

// ---------------------------------------------------------------------------
// Tiled f32 GEMM:  out = A(MxK) @ W(NxK)^T + bias, with epilogues.
//   EPI 0: QKV scatter into [win][which][head][l][d] layout
//   EPI 1: out-proj: window-merge + residual add (res = original x), write d_out
//   EPI 2: exact GELU, write out[row*N+col]
//   EPI 3: final: out[row*256+col] = res[row*256+col] + val  (res == d_out)
// BM=BN=64, BK=16, 256 threads, each thread computes 4x4.
// ---------------------------------------------------------------------------
#define BM 64
#define BN 64
#define BK 16

template <int EPI>
__global__ __launch_bounds__(256) void gemm_kernel(
    const float* __restrict__ A, const float* __restrict__ W,
    const float* __restrict__ bias, float* __restrict__ out,
    const float* __restrict__ res, int M, int N, int K)
{
    __shared__ __align__(16) float As[BK][BM + 4];
    __shared__ __align__(16) float Bs[BK][BN + 4];
    int tid = threadIdx.x;
    int bm = blockIdx.x * BM;
    int bn = blockIdx.y * BN;
    int tx = tid & 15, ty = tid >> 4;
    int lrow = tid >> 2;             // 0..63
    int lk4  = (tid & 3) * 4;        // 0,4,8,12

    float acc[4][4] = {};

    for (int k0 = 0; k0 < K; k0 += BK) {
        float4 a4 = *(const float4*)(A + (size_t)(bm + lrow) * K + k0 + lk4);
        float4 b4 = *(const float4*)(W + (size_t)(bn + lrow) * K + k0 + lk4);
        As[lk4 + 0][lrow] = a4.x;
        As[lk4 + 1][lrow] = a4.y;
        As[lk4 + 2][lrow] = a4.z;
        As[lk4 + 3][lrow] = a4.w;
        Bs[lk4 + 0][lrow] = b4.x;
        Bs[lk4 + 1][lrow] = b4.y;
        Bs[lk4 + 2][lrow] = b4.z;
        Bs[lk4 + 3][lrow] = b4.w;
        __syncthreads();
        #pragma unroll
        for (int kk = 0; kk < BK; ++kk) {
            float4 av = *(const float4*)&As[kk][ty * 4];
            float4 bv = *(const float4*)&Bs[kk][tx * 4];
            float a[4] = {av.x, av.y, av.z, av.w};
            float b[4] = {bv.x, bv.y, bv.z, bv.w};
            #pragma unroll
            for (int i = 0; i < 4; ++i)
                #pragma unroll
                for (int j = 0; j < 4; ++j)
                    acc[i][j] += a[i] * b[j];
        }
        __syncthreads();
    }

    #pragma unroll
    for (int i = 0; i < 4; ++i) {
        int row = bm + ty * 4 + i;
        #pragma unroll
        for (int j = 0; j < 4; ++j) {
            int col = bn + tx * 4 + j;
            float val = acc[i][j] + bias[col];
            if (EPI == 0) {
                // scatter qkv: col = which*256 + head*32 + d ; row = win*49 + l
                int which = col >> 8;
                int rem = col & 255;
                int head = rem >> 5;
                int d = rem & 31;
                int win = row / L_, l = row % L_;
                size_t off = (((size_t)(win * 3 + which) * HEADS_ + head) * L_ + l) * HD + d;
                out[off] = val;
            } else if (EPI == 1) {
                // window merge + residual
                int win = row / L_, l = row % L_;
                int b_ = win >> 6;
                int wh = (win >> 3) & 7;
                int ww = win & 7;
                int y = wh * WS_ + l / WS_;
                int xc = ww * WS_ + l % WS_;
                size_t r = (size_t)b_ * NTOK + y * WW_ + xc;
                out[r * C_ + col] = val + res[r * C_ + col];
            } else if (EPI == 2) {
                // exact GELU
                float g = 0.5f * val * (1.0f + erff(val * 0.70710678118654752f));
                out[(size_t)row * N + col] = g;
            } else {
                // final residual: res == out buffer holding x1
                size_t idx = (size_t)row * C_ + col;
                out[idx] = res[idx] + val;
            }
        }
    }
}

// ---------------------------------------------------------------------------
// Window attention: one block (64 threads) per (window, head).
// K,V staged in LDS; lanes 0..48 each own one query row.
// ---------------------------------------------------------------------------
__global__ __launch_bounds__(64) void attn_kernel(
    const float* __restrict__ qkv, float* __restrict__ o_win)
{
    __shared__ __align__(16) float ks[L_][HD];
    __shared__ __align__(16) float vs[L_][HD];
    int wh = blockIdx.x;
    int win = wh >> 3, head = wh & 7;
    size_t qbase = ((size_t)(win * 3 + 0) * HEADS_ + head) * (L_ * HD);
    size_t kbase = ((size_t)(win * 3 + 1) * HEADS_ + head) * (L_ * HD);
    size_t vbase = ((size_t)(win * 3 + 2) * HEADS_ + head) * (L_ * HD);
    int lane = threadIdx.x;
    for (int i = lane; i < (L_ * HD) / 4; i += 64) {
        ((float4*)&ks[0][0])[i] = *(const float4*)(qkv + kbase + (size_t)i * 4);
        ((float4*)&vs[0][0])[i] = *(const float4*)(qkv + vbase + (size_t)i * 4);
    }
    __syncthreads();
    if (lane < L_) {
        float q[HD];
        const float* qp = qkv + qbase + lane * HD;
        #pragma unroll
        for (int d = 0; d < HD; d += 4) {
            float4 t = *(const float4*)(qp + d);
            q[d] = t.x; q[d + 1] = t.y; q[d + 2] = t.z; q[d + 3] = t.w;
        }
        float s[L_];
        float mx = -1e30f;
        #pragma unroll
        for (int j = 0; j < L_; ++j) {
            float a = 0.0f;
            #pragma unroll
            for (int d = 0; d < HD; ++d) a += q[d] * ks[j][d];
            s[j] = a * 0.17677669529663687f;   // 1/sqrt(32)
            mx = fmaxf(mx, s[j]);
        }
        float sum = 0.0f;
        #pragma unroll
        for (int j = 0; j < L_; ++j) {
            s[j] = __expf(s[j] - mx);
            sum += s[j];
        }
        float inv = 1.0f / sum;
        float o[HD] = {};
        #pragma unroll
        for (int j = 0; j < L_; ++j) {
            float p = s[j];
            #pragma unroll
            for (int d = 0; d < HD; ++d) o[d] += p * vs[j][d];
        }
        int t = win * L_ + lane;
        float* op = o_win + (size_t)t * C_ + head * HD;
        #pragma unroll
        for (int d = 0; d < HD; d += 4) {
            float4 ov;
            ov.x = o[d] * inv; ov.y = o[d + 1] * inv;
            ov.z = o[d + 2] * inv; ov.w = o[d + 3] * inv;
            *(float4*)(op + d) = ov;
        }
    }
}

// ---------------------------------------------------------------------------
extern "C" void kernel_launch(void* const* d_in, const int* in_sizes, int n_in,
                              void* d_out, int out_size, void* d_ws, size_t ws_size,
                              hipStream_t stream)
{
    (void)in_sizes; (void)n_in; (void)out_size; (void)ws_size;
    const float* x    = (const float*)d_in[0];
    // d_in[1], d_in[2] are H, W scalars (56, 56) — hardcoded
    const float* n1g  = (const float*)d_in[3];
    const float* n1b  = (const float*)d_in[4];
    const float* wqkv = (const float*)d_in[5];
    const float* bqkv = (const float*)d_in[6];
    const float* wout = (const float*)d_in[7];
    const float* bout = (const float*)d_in[8];
    const float* n2g  = (const float*)d_in[9];
    const float* n2b  = (const float*)d_in[10];
    const float* w1   = (const float*)d_in[11];
    const float* b1   = (const float*)d_in[12];
    const float* w2   = (const float*)d_in[13];
    const float* b2   = (const float*)d_in[14];
    float* out = (float*)d_out;

    float* bufA = (float*)d_ws;                       // M_*256 floats (102.8 MB)
    float* bufB = bufA + (size_t)M_ * C_;             // M_*768 floats (308.3 MB)

    // 1) LN1 + window partition -> bufA (windowed rows)
    ln_kernel<1><<<M_ / 4, 256, 0, stream>>>(x, n1g, n1b, bufA);

    // 2) QKV GEMM: bufA (M x 256) @ in_proj_w^T (768x256) -> scatter to bufB
    gemm_kernel<0><<<dim3(M_ / BM, (3 * C_) / BN), 256, 0, stream>>>(
        bufA, wqkv, bqkv, bufB, nullptr, M_, 3 * C_, C_);

    // 3) attention per (window, head) -> o_win in bufA (t x 256 layout)
    attn_kernel<<<NWIN * HEADS_, 64, 0, stream>>>(bufB, bufA);

    // 4) out-proj + window merge + residual -> d_out holds x1
    gemm_kernel<1><<<dim3(M_ / BM, C_ / BN), 256, 0, stream>>>(
        bufA, wout, bout, out, x, M_, C_, C_);

    // 5) LN2 on x1 -> bufA
    ln_kernel<0><<<M_ / 4, 256, 0, stream>>>(out, n2g, n2b, bufA);

    // 6) MLP fc1 + exact GELU -> bufB (M x 512)
    gemm_kernel<2><<<dim3(M_ / BM, MLPH / BN), 256, 0, stream>>>(
        bufA, w1, b1, bufB, nullptr, M_, MLPH, C_);

    // 7) MLP fc2 + bias + residual(x1 in d_out) -> d_out final
    gemm_kernel<3><<<dim3(M_ / BM, C_ / BN), 256, 0, stream>>>(
        bufB, w2, b2, out, out, M_, C_, MLPH);
}

// Round 2
// 593.895 us; speedup vs baseline: 2.8817x; 2.8817x over previous
//
#include <hip/hip_runtime.h>
#include <hip/hip_bf16.h>
#include <math.h>

// Problem constants (B=32, H=W=56, C=256, heads=8, hd=32, ws=7)
#define NTOK 3136            // 56*56
#define C_ 256
#define HEADS_ 8
#define HD 32
#define WS_ 7
#define L_ 49
#define NWIN 2048            // 32 * 8 * 8
#define M_ 100352            // NWIN * 49  == BATCH*NTOK
#define MLPH 512

typedef __bf16 bf16x8 __attribute__((ext_vector_type(8)));
typedef float f32x4 __attribute__((ext_vector_type(4)));

__device__ __forceinline__ unsigned short f2bf(float f) {
    union { float f; unsigned u; } v; v.f = f;
    unsigned r = v.u + 0x7fffu + ((v.u >> 16) & 1u);   // RNE
    return (unsigned short)(r >> 16);
}
__device__ __forceinline__ float bf2f(unsigned short s) {
    union { unsigned u; float f; } v; v.u = ((unsigned)s) << 16;
    return v.f;
}

// ---------------------------------------------------------------------------
// f32 -> bf16 conversion (weights)
// ---------------------------------------------------------------------------
__global__ __launch_bounds__(256) void cvt_kernel(
    const float* __restrict__ in, unsigned short* __restrict__ out, int n)
{
    int i = blockIdx.x * 256 + threadIdx.x;
    if (i < n) out[i] = f2bf(in[i]);
}

// ---------------------------------------------------------------------------
// LayerNorm: one wave per token, 4 floats/lane; bf16 output.
// WINDOWED=1: write rows window-partitioned (LN1 -> QKV GEMM A).
// ---------------------------------------------------------------------------
template <int WINDOWED>
__global__ __launch_bounds__(256) void ln_kernel(
    const float* __restrict__ x, const float* __restrict__ gamma,
    const float* __restrict__ beta, unsigned short* __restrict__ out)
{
    int wave = threadIdx.x >> 6;
    int lane = threadIdx.x & 63;
    int p = blockIdx.x * 4 + wave;
    const float* row = x + (size_t)p * C_;
    float4 v = *(const float4*)(row + lane * 4);
    float s  = v.x + v.y + v.z + v.w;
    float ss = v.x * v.x + v.y * v.y + v.z * v.z + v.w * v.w;
    #pragma unroll
    for (int m = 1; m < 64; m <<= 1) {
        s  += __shfl_xor(s, m, 64);
        ss += __shfl_xor(ss, m, 64);
    }
    float mean = s * (1.0f / C_);
    float var  = ss * (1.0f / C_) - mean * mean;
    float inv  = rsqrtf(var + 1e-5f);
    float4 gv = *(const float4*)(gamma + lane * 4);
    float4 bv = *(const float4*)(beta + lane * 4);
    size_t orow;
    if (WINDOWED) {
        int b_ = p / NTOK, n = p % NTOK;
        int y = n / 56, xc = n % 56;
        int win = (b_ * 8 + y / WS_) * 8 + xc / WS_;
        int l   = (y % WS_) * WS_ + (xc % WS_);
        orow = (size_t)(win * L_ + l) * C_;
    } else {
        orow = (size_t)p * C_;
    }
    unsigned short o[4];
    o[0] = f2bf((v.x - mean) * inv * gv.x + bv.x);
    o[1] = f2bf((v.y - mean) * inv * gv.y + bv.y);
    o[2] = f2bf((v.z - mean) * inv * gv.z + bv.z);
    o[3] = f2bf((v.w - mean) * inv * gv.w + bv.w);
    *(uint2*)(out + orow + lane * 4) = *(const uint2*)o;
}

// ---------------------------------------------------------------------------
// bf16 MFMA GEMM (m97 structure): out = A(MxK) @ W(NxK)^T + bias, epilogues.
// 128x128 tile, BK=32, 256 threads (4 waves), each wave 64x64 (4x4 frags of
// 16x16x32). global_load_lds width=16 staging, 2-barrier K-loop.
//   EPI 0: QKV scatter -> bf16 [win][which][head][l][d]
//   EPI 1: out-proj: window-merge + residual(res=x f32) -> f32 out
//   EPI 2: exact GELU -> bf16 out[row*N+col]
//   EPI 3: final residual: f32 out = res + val (res == out buffer, x1)
// ---------------------------------------------------------------------------
#define GBM 128
#define GBN 128
#define GBK 32

__device__ __forceinline__ void gload_lds16(const void* g, void* l) {
    __builtin_amdgcn_global_load_lds(
        (const __attribute__((address_space(1))) unsigned*)g,
        (__attribute__((address_space(3))) unsigned*)l, 16, 0, 0);
}

template <int EPI>
__global__ __launch_bounds__(256) void mgemm(
    const unsigned short* __restrict__ A, const unsigned short* __restrict__ W,
    const float* __restrict__ bias, void* __restrict__ outv,
    const float* __restrict__ res, int M, int N, int K)
{
    __shared__ __align__(16) unsigned short As[GBM * GBK];  // 8 KB
    __shared__ __align__(16) unsigned short Bs[GBN * GBK];  // 8 KB

    int tid  = threadIdx.x;
    int w    = tid >> 6;        // wave 0..3
    int lane = tid & 63;
    int wr = w >> 1, wc = w & 1;
    int bm = blockIdx.x * GBM;
    int bn = blockIdx.y * GBN;

    // staging geometry: each wave covers 32 rows (2 x 1KB loads) of A and B
    int srow = lane >> 2;            // 0..15 row within 16-row chunk
    int scol = (lane & 3) * 8;       // bf16 element offset of 16B chunk

    f32x4 acc[4][4] = {};

    for (int k0 = 0; k0 < K; k0 += GBK) {
        #pragma unroll
        for (int i = 0; i < 2; ++i) {
            int ra = w * 32 + i * 16;
            gload_lds16(A + (size_t)(bm + ra + srow) * K + k0 + scol,
                        &As[ra * GBK]);
            gload_lds16(W + (size_t)(bn + ra + srow) * K + k0 + scol,
                        &Bs[ra * GBK]);
        }
        __syncthreads();   // drains vmcnt before barrier (compiler-inserted)

        bf16x8 af[4], bf[4];
        #pragma unroll
        for (int mi = 0; mi < 4; ++mi)
            af[mi] = *(const bf16x8*)&As[(wr * 64 + mi * 16 + (lane & 15)) * GBK + (lane >> 4) * 8];
        #pragma unroll
        for (int ni = 0; ni < 4; ++ni)
            bf[ni] = *(const bf16x8*)&Bs[(wc * 64 + ni * 16 + (lane & 15)) * GBK + (lane >> 4) * 8];

        #pragma unroll
        for (int mi = 0; mi < 4; ++mi)
            #pragma unroll
            for (int ni = 0; ni < 4; ++ni)
                acc[mi][ni] = __builtin_amdgcn_mfma_f32_16x16x32_bf16(
                    af[mi], bf[ni], acc[mi][ni], 0, 0, 0);
        __syncthreads();
    }

    // epilogue: C/D layout col=lane&15, row=(lane>>4)*4+reg  [m89-verified]
    #pragma unroll
    for (int mi = 0; mi < 4; ++mi) {
        #pragma unroll
        for (int ni = 0; ni < 4; ++ni) {
            int col = bn + wc * 64 + ni * 16 + (lane & 15);
            float bv = bias[col];
            #pragma unroll
            for (int r = 0; r < 4; ++r) {
                int row = bm + wr * 64 + mi * 16 + (lane >> 4) * 4 + r;
                float val = acc[mi][ni][r] + bv;
                if (EPI == 0) {
                    int which = col >> 8;
                    int head  = (col >> 5) & 7;
                    int d     = col & 31;
                    int win = row / L_, l = row - win * L_;
                    ((unsigned short*)outv)[(((size_t)(win * 3 + which) * HEADS_ + head) * L_ + l) * HD + d] = f2bf(val);
                } else if (EPI == 1) {
                    int win = row / L_, l = row - win * L_;
                    int b_ = win >> 6, wh = (win >> 3) & 7, ww = win & 7;
                    int y  = wh * WS_ + l / WS_;
                    int xc = ww * WS_ + l % WS_;
                    size_t rr = (size_t)b_ * NTOK + y * 56 + xc;
                    ((float*)outv)[rr * C_ + col] = val + res[rr * C_ + col];
                } else if (EPI == 2) {
                    float g = 0.5f * val * (1.0f + erff(val * 0.70710678118654752f));
                    ((unsigned short*)outv)[(size_t)row * N + col] = f2bf(g);
                } else {
                    size_t idx = (size_t)row * C_ + col;
                    ((float*)outv)[idx] = res[idx] + val;
                }
            }
        }
    }
}

// ---------------------------------------------------------------------------
// Window attention: one block (1 wave) per (window, head). bf16 in/out,
// f32 compute. K,V staged to LDS as f32; lanes 0..48 own one query row.
// ---------------------------------------------------------------------------
__global__ __launch_bounds__(64) void attn_kernel(
    const unsigned short* __restrict__ qkv, unsigned short* __restrict__ o_win)
{
    __shared__ __align__(16) float ks[L_ * HD];
    __shared__ __align__(16) float vs[L_ * HD];
    int wh = blockIdx.x;
    int win = wh >> 3, head = wh & 7;
    size_t qbase = ((size_t)(win * 3 + 0) * HEADS_ + head) * (L_ * HD);
    size_t kbase = ((size_t)(win * 3 + 1) * HEADS_ + head) * (L_ * HD);
    size_t vbase = ((size_t)(win * 3 + 2) * HEADS_ + head) * (L_ * HD);
    int lane = threadIdx.x;

    for (int i = lane; i < (L_ * HD) / 8; i += 64) {   // 196 chunks of 8 bf16
        uint4 kr = *(const uint4*)(qkv + kbase + (size_t)i * 8);
        uint4 vr = *(const uint4*)(qkv + vbase + (size_t)i * 8);
        float* kd = &ks[i * 8];
        float* vd = &vs[i * 8];
        kd[0] = bf2f(kr.x & 0xffff); kd[1] = bf2f(kr.x >> 16);
        kd[2] = bf2f(kr.y & 0xffff); kd[3] = bf2f(kr.y >> 16);
        kd[4] = bf2f(kr.z & 0xffff); kd[5] = bf2f(kr.z >> 16);
        kd[6] = bf2f(kr.w & 0xffff); kd[7] = bf2f(kr.w >> 16);
        vd[0] = bf2f(vr.x & 0xffff); vd[1] = bf2f(vr.x >> 16);
        vd[2] = bf2f(vr.y & 0xffff); vd[3] = bf2f(vr.y >> 16);
        vd[4] = bf2f(vr.z & 0xffff); vd[5] = bf2f(vr.z >> 16);
        vd[6] = bf2f(vr.w & 0xffff); vd[7] = bf2f(vr.w >> 16);
    }
    __syncthreads();

    if (lane < L_) {
        float q[HD];
        const unsigned short* qp = qkv + qbase + (size_t)lane * HD;
        #pragma unroll
        for (int g = 0; g < 4; ++g) {
            uint4 qr = *(const uint4*)(qp + g * 8);
            q[g * 8 + 0] = bf2f(qr.x & 0xffff); q[g * 8 + 1] = bf2f(qr.x >> 16);
            q[g * 8 + 2] = bf2f(qr.y & 0xffff); q[g * 8 + 3] = bf2f(qr.y >> 16);
            q[g * 8 + 4] = bf2f(qr.z & 0xffff); q[g * 8 + 5] = bf2f(qr.z >> 16);
            q[g * 8 + 6] = bf2f(qr.w & 0xffff); q[g * 8 + 7] = bf2f(qr.w >> 16);
        }
        float s[L_];
        float mx = -1e30f;
        #pragma unroll
        for (int j = 0; j < L_; ++j) {
            float a = 0.0f;
            #pragma unroll
            for (int d = 0; d < HD; d += 4) {
                float4 kv = *(const float4*)&ks[j * HD + d];
                a += q[d] * kv.x + q[d + 1] * kv.y + q[d + 2] * kv.z + q[d + 3] * kv.w;
            }
            s[j] = a * 0.17677669529663687f;   // 1/sqrt(32)
            mx = fmaxf(mx, s[j]);
        }
        float sum = 0.0f;
        #pragma unroll
        for (int j = 0; j < L_; ++j) {
            s[j] = __expf(s[j] - mx);
            sum += s[j];
        }
        float inv = 1.0f / sum;
        float o[HD] = {};
        #pragma unroll
        for (int j = 0; j < L_; ++j) {
            float p = s[j];
            #pragma unroll
            for (int d = 0; d < HD; d += 4) {
                float4 vv = *(const float4*)&vs[j * HD + d];
                o[d] += p * vv.x; o[d + 1] += p * vv.y;
                o[d + 2] += p * vv.z; o[d + 3] += p * vv.w;
            }
        }
        int t = win * L_ + lane;
        unsigned short* op = o_win + (size_t)t * C_ + head * HD;
        #pragma unroll
        for (int g = 0; g < 4; ++g) {
            uint4 wv;
            wv.x = (unsigned)f2bf(o[g * 8 + 0] * inv) | ((unsigned)f2bf(o[g * 8 + 1] * inv) << 16);
            wv.y = (unsigned)f2bf(o[g * 8 + 2] * inv) | ((unsigned)f2bf(o[g * 8 + 3] * inv) << 16);
            wv.z = (unsigned)f2bf(o[g * 8 + 4] * inv) | ((unsigned)f2bf(o[g * 8 + 5] * inv) << 16);
            wv.w = (unsigned)f2bf(o[g * 8 + 6] * inv) | ((unsigned)f2bf(o[g * 8 + 7] * inv) << 16);
            *(uint4*)(op + g * 8) = wv;
        }
    }
}

// ---------------------------------------------------------------------------
extern "C" void kernel_launch(void* const* d_in, const int* in_sizes, int n_in,
                              void* d_out, int out_size, void* d_ws, size_t ws_size,
                              hipStream_t stream)
{
    (void)in_sizes; (void)n_in; (void)out_size; (void)ws_size;
    const float* x    = (const float*)d_in[0];
    const float* n1g  = (const float*)d_in[3];
    const float* n1b  = (const float*)d_in[4];
    const float* wqkv = (const float*)d_in[5];
    const float* bqkv = (const float*)d_in[6];
    const float* wout = (const float*)d_in[7];
    const float* bout = (const float*)d_in[8];
    const float* n2g  = (const float*)d_in[9];
    const float* n2b  = (const float*)d_in[10];
    const float* w1   = (const float*)d_in[11];
    const float* b1   = (const float*)d_in[12];
    const float* w2   = (const float*)d_in[13];
    const float* b2   = (const float*)d_in[14];
    float* out = (float*)d_out;

    // workspace layout (bf16 shorts)
    unsigned short* bufA_bf = (unsigned short*)d_ws;               // M*256
    unsigned short* qkv_bf  = bufA_bf + (size_t)M_ * C_;           // M*768 (aliased by gelu out M*512)
    unsigned short* wqkv_bf = qkv_bf + (size_t)M_ * 3 * C_;
    unsigned short* wout_bf = wqkv_bf + 768 * 256;
    unsigned short* w1_bf   = wout_bf + 256 * 256;
    unsigned short* w2_bf   = w1_bf + 512 * 256;

    // 0) weights -> bf16
    cvt_kernel<<<(768 * 256 + 255) / 256, 256, 0, stream>>>(wqkv, wqkv_bf, 768 * 256);
    cvt_kernel<<<(256 * 256 + 255) / 256, 256, 0, stream>>>(wout, wout_bf, 256 * 256);
    cvt_kernel<<<(512 * 256 + 255) / 256, 256, 0, stream>>>(w1, w1_bf, 512 * 256);
    cvt_kernel<<<(256 * 512 + 255) / 256, 256, 0, stream>>>(w2, w2_bf, 256 * 512);

    // 1) LN1 + window partition -> bufA_bf
    ln_kernel<1><<<M_ / 4, 256, 0, stream>>>(x, n1g, n1b, bufA_bf);

    // 2) QKV GEMM -> scattered bf16 qkv
    mgemm<0><<<dim3(M_ / GBM, (3 * C_) / GBN), 256, 0, stream>>>(
        bufA_bf, wqkv_bf, bqkv, qkv_bf, nullptr, M_, 3 * C_, C_);

    // 3) window attention -> o_win (bufA_bf, windowed token x 256)
    attn_kernel<<<NWIN * HEADS_, 64, 0, stream>>>(qkv_bf, bufA_bf);

    // 4) out-proj + window merge + residual -> d_out = x1 (f32)
    mgemm<1><<<dim3(M_ / GBM, C_ / GBN), 256, 0, stream>>>(
        bufA_bf, wout_bf, bout, out, x, M_, C_, C_);

    // 5) LN2 -> bufA_bf
    ln_kernel<0><<<M_ / 4, 256, 0, stream>>>(out, n2g, n2b, bufA_bf);

    // 6) MLP fc1 + GELU -> qkv_bf region (M x 512 bf16)
    mgemm<2><<<dim3(M_ / GBM, MLPH / GBN), 256, 0, stream>>>(
        bufA_bf, w1_bf, b1, qkv_bf, nullptr, M_, MLPH, C_);

    // 7) MLP fc2 + residual(x1) -> d_out
    mgemm<3><<<dim3(M_ / GBM, C_ / GBN), 256, 0, stream>>>(
        qkv_bf, w2_bf, b2, out, out, M_, C_, MLPH);
}

// Round 3
// 453.981 us; speedup vs baseline: 3.7698x; 1.3082x over previous
//
#include <hip/hip_runtime.h>
#include <hip/hip_bf16.h>
#include <math.h>

// Problem constants (B=32, H=W=56, C=256, heads=8, hd=32, ws=7)
#define NTOK 3136            // 56*56
#define C_ 256
#define HEADS_ 8
#define HD 32
#define WS_ 7
#define L_ 49
#define NWIN 2048            // 32 * 8 * 8
#define NWH 16384            // NWIN * HEADS_
#define M_ 100352            // NWIN * 49  == BATCH*NTOK
#define MLPH 512
#define WHSZ 2048            // 64 (padded L) * 32 (hd) elems per (win,head) plane

typedef __bf16 bf16x8 __attribute__((ext_vector_type(8)));
typedef float f32x4 __attribute__((ext_vector_type(4)));

__device__ __forceinline__ unsigned short f2bf(float f) {
    union { float f; unsigned u; } v; v.f = f;
    unsigned r = v.u + 0x7fffu + ((v.u >> 16) & 1u);   // RNE
    return (unsigned short)(r >> 16);
}
__device__ __forceinline__ float bf2f(unsigned short s) {
    union { unsigned u; float f; } v; v.u = ((unsigned)s) << 16;
    return v.f;
}

// ---------------------------------------------------------------------------
// f32 -> bf16 conversion (weights)
// ---------------------------------------------------------------------------
__global__ __launch_bounds__(256) void cvt_kernel(
    const float* __restrict__ in, unsigned short* __restrict__ out, int n)
{
    int i = blockIdx.x * 256 + threadIdx.x;
    if (i < n) out[i] = f2bf(in[i]);
}

// ---------------------------------------------------------------------------
// LayerNorm: one wave per token, 4 floats/lane; bf16 output.
// WINDOWED=1: write rows window-partitioned (LN1 -> QKV GEMM A).
// ---------------------------------------------------------------------------
template <int WINDOWED>
__global__ __launch_bounds__(256) void ln_kernel(
    const float* __restrict__ x, const float* __restrict__ gamma,
    const float* __restrict__ beta, unsigned short* __restrict__ out)
{
    int wave = threadIdx.x >> 6;
    int lane = threadIdx.x & 63;
    int p = blockIdx.x * 4 + wave;
    const float* row = x + (size_t)p * C_;
    float4 v = *(const float4*)(row + lane * 4);
    float s  = v.x + v.y + v.z + v.w;
    float ss = v.x * v.x + v.y * v.y + v.z * v.z + v.w * v.w;
    #pragma unroll
    for (int m = 1; m < 64; m <<= 1) {
        s  += __shfl_xor(s, m, 64);
        ss += __shfl_xor(ss, m, 64);
    }
    float mean = s * (1.0f / C_);
    float var  = ss * (1.0f / C_) - mean * mean;
    float inv  = rsqrtf(var + 1e-5f);
    float4 gv = *(const float4*)(gamma + lane * 4);
    float4 bv = *(const float4*)(beta + lane * 4);
    size_t orow;
    if (WINDOWED) {
        int b_ = p / NTOK, n = p % NTOK;
        int y = n / 56, xc = n % 56;
        int win = (b_ * 8 + y / WS_) * 8 + xc / WS_;
        int l   = (y % WS_) * WS_ + (xc % WS_);
        orow = (size_t)(win * L_ + l) * C_;
    } else {
        orow = (size_t)p * C_;
    }
    unsigned short o[4];
    o[0] = f2bf((v.x - mean) * inv * gv.x + bv.x);
    o[1] = f2bf((v.y - mean) * inv * gv.y + bv.y);
    o[2] = f2bf((v.z - mean) * inv * gv.z + bv.z);
    o[3] = f2bf((v.w - mean) * inv * gv.w + bv.w);
    *(uint2*)(out + orow + lane * 4) = *(const uint2*)o;
}

// ---------------------------------------------------------------------------
// bf16 MFMA GEMM (m97 structure): out = A(MxK) @ W(NxK)^T + bias, epilogues.
// 128x128 tile, BK=32, 256 threads (4 waves), wave computes 64x64 via 4x4
// frags of 16x16x32. global_load_lds width=16 staging, 2-barrier K-loop.
//   EPI 0: QKV scatter -> bf16 planes: Q[wh][l64][d32], K same,
//          V' pre-fragmented [wh][kb=l>>3][d32][kj=l&7]
//   EPI 1: out-proj: window-merge + residual(res=x f32) -> f32 out
//   EPI 2: exact GELU -> bf16 out[row*N+col]
//   EPI 3: final residual: f32 out = res + val (res == out buffer, x1)
// ---------------------------------------------------------------------------
#define GBM 128
#define GBN 128
#define GBK 32

__device__ __forceinline__ void gload_lds16(const void* g, void* l) {
    __builtin_amdgcn_global_load_lds(
        (const __attribute__((address_space(1))) unsigned*)g,
        (__attribute__((address_space(3))) unsigned*)l, 16, 0, 0);
}

template <int EPI>
__global__ __launch_bounds__(256) void mgemm(
    const unsigned short* __restrict__ A, const unsigned short* __restrict__ W,
    const float* __restrict__ bias, void* __restrict__ outv,
    const float* __restrict__ res, int M, int N, int K)
{
    __shared__ __align__(16) unsigned short As[GBM * GBK];  // 8 KB
    __shared__ __align__(16) unsigned short Bs[GBN * GBK];  // 8 KB

    int tid  = threadIdx.x;
    int w    = tid >> 6;        // wave 0..3
    int lane = tid & 63;
    int wr = w >> 1, wc = w & 1;
    int bm = blockIdx.x * GBM;
    int bn = blockIdx.y * GBN;

    int srow = lane >> 2;            // 0..15 row within 16-row chunk
    int scol = (lane & 3) * 8;       // bf16 element offset of 16B chunk

    f32x4 acc[4][4] = {};

    for (int k0 = 0; k0 < K; k0 += GBK) {
        #pragma unroll
        for (int i = 0; i < 2; ++i) {
            int ra = w * 32 + i * 16;
            gload_lds16(A + (size_t)(bm + ra + srow) * K + k0 + scol,
                        &As[ra * GBK]);
            gload_lds16(W + (size_t)(bn + ra + srow) * K + k0 + scol,
                        &Bs[ra * GBK]);
        }
        __syncthreads();

        bf16x8 af[4], bf[4];
        #pragma unroll
        for (int mi = 0; mi < 4; ++mi)
            af[mi] = *(const bf16x8*)&As[(wr * 64 + mi * 16 + (lane & 15)) * GBK + (lane >> 4) * 8];
        #pragma unroll
        for (int ni = 0; ni < 4; ++ni)
            bf[ni] = *(const bf16x8*)&Bs[(wc * 64 + ni * 16 + (lane & 15)) * GBK + (lane >> 4) * 8];

        #pragma unroll
        for (int mi = 0; mi < 4; ++mi)
            #pragma unroll
            for (int ni = 0; ni < 4; ++ni)
                acc[mi][ni] = __builtin_amdgcn_mfma_f32_16x16x32_bf16(
                    af[mi], bf[ni], acc[mi][ni], 0, 0, 0);
        __syncthreads();
    }

    // epilogue: C/D layout col=lane&15, row=(lane>>4)*4+reg  [m89-verified]
    #pragma unroll
    for (int mi = 0; mi < 4; ++mi) {
        #pragma unroll
        for (int ni = 0; ni < 4; ++ni) {
            int col = bn + wc * 64 + ni * 16 + (lane & 15);
            float bv = bias[col];
            #pragma unroll
            for (int r = 0; r < 4; ++r) {
                int row = bm + wr * 64 + mi * 16 + (lane >> 4) * 4 + r;
                float val = acc[mi][ni][r] + bv;
                if (EPI == 0) {
                    int which = col >> 8;
                    int head  = (col >> 5) & 7;
                    int d     = col & 31;
                    int win = row / L_, l = row - win * L_;
                    int wh = win * HEADS_ + head;
                    size_t base = (size_t)which * ((size_t)NWH * WHSZ) + (size_t)wh * WHSZ;
                    size_t off;
                    if (which == 2)
                        off = base + (size_t)(((l >> 3) * HD + d) << 3) + (l & 7);
                    else
                        off = base + (size_t)l * HD + d;
                    ((unsigned short*)outv)[off] = f2bf(val);
                } else if (EPI == 1) {
                    int win = row / L_, l = row - win * L_;
                    int b_ = win >> 6, wh_ = (win >> 3) & 7, ww = win & 7;
                    int y  = wh_ * WS_ + l / WS_;
                    int xc = ww * WS_ + l % WS_;
                    size_t rr = (size_t)b_ * NTOK + y * 56 + xc;
                    ((float*)outv)[rr * C_ + col] = val + res[rr * C_ + col];
                } else if (EPI == 2) {
                    float g = 0.5f * val * (1.0f + erff(val * 0.70710678118654752f));
                    ((unsigned short*)outv)[(size_t)row * N + col] = f2bf(g);
                } else {
                    size_t idx = (size_t)row * C_ + col;
                    ((float*)outv)[idx] = res[idx] + val;
                }
            }
        }
    }
}

// ---------------------------------------------------------------------------
// MFMA window attention: 4 waves/block, each wave one (win,head).
// S = Q@K^T via 4x4 tiles of 16x16x32 (L=49 padded to 64, masked cols).
// Wave-parallel softmax (shfl_xor within 16-lane groups). P -> LDS (row-major,
// stride 72). O = P@V via 4x2 tiles x 2 ksteps; V pre-fragmented layout.
// No barriers: wave-private LDS slice, in-wave DS FIFO ordering.
// ---------------------------------------------------------------------------
__global__ __launch_bounds__(256) void mattn(
    const unsigned short* __restrict__ qkv, unsigned short* __restrict__ o_win)
{
    __shared__ __align__(16) unsigned short P_lds[4][64][72];   // 36.9 KB
    int wave = threadIdx.x >> 6, lane = threadIdx.x & 63;
    int c = lane & 15, hi = lane >> 4;
    int wh = blockIdx.x * 4 + wave;
    int win = wh >> 3, head = wh & 7;
    const unsigned short* qb = qkv + (size_t)wh * WHSZ;
    const unsigned short* kb = qb + (size_t)NWH * WHSZ;
    const unsigned short* vb = kb + (size_t)NWH * WHSZ;

    // S = Q @ K^T   (A: row=q=lane&15, k=(lane>>4)*8+j ; B: col=key)
    bf16x8 af[4], bk[4];
    #pragma unroll
    for (int mi = 0; mi < 4; ++mi)
        af[mi] = *(const bf16x8*)(qb + (mi * 16 + c) * HD + hi * 8);
    #pragma unroll
    for (int ni = 0; ni < 4; ++ni)
        bk[ni] = *(const bf16x8*)(kb + (ni * 16 + c) * HD + hi * 8);

    f32x4 sacc[4][4] = {};
    #pragma unroll
    for (int mi = 0; mi < 4; ++mi)
        #pragma unroll
        for (int ni = 0; ni < 4; ++ni)
            sacc[mi][ni] = __builtin_amdgcn_mfma_f32_16x16x32_bf16(
                af[mi], bk[ni], sacc[mi][ni], 0, 0, 0);

    // softmax rows (C/D: row=(lane>>4)*4+r+mi*16, col=ni*16+(lane&15))
    const float scale = 0.17677669529663687f;   // 1/sqrt(32)
    float inv_[4][4];
    #pragma unroll
    for (int mi = 0; mi < 4; ++mi) {
        #pragma unroll
        for (int r = 0; r < 4; ++r) {
            float sv[4];
            float m = -1e30f;
            #pragma unroll
            for (int ni = 0; ni < 4; ++ni) {
                float v = sacc[mi][ni][r] * scale;
                v = (ni * 16 + c < L_) ? v : -1e30f;
                sv[ni] = v;
                m = fmaxf(m, v);
            }
            #pragma unroll
            for (int msk = 1; msk < 16; msk <<= 1)
                m = fmaxf(m, __shfl_xor(m, msk, 64));
            float sum = 0.f;
            unsigned short pb[4];
            #pragma unroll
            for (int ni = 0; ni < 4; ++ni) {
                float p = __expf(sv[ni] - m);
                sum += p;
                pb[ni] = f2bf(p);
            }
            #pragma unroll
            for (int msk = 1; msk < 16; msk <<= 1)
                sum += __shfl_xor(sum, msk, 64);
            inv_[mi][r] = 1.0f / sum;
            int q = mi * 16 + hi * 4 + r;
            #pragma unroll
            for (int ni = 0; ni < 4; ++ni)
                P_lds[wave][q][ni * 16 + c] = pb[ni];
        }
    }

    // O = P @ V  (A: P rows from LDS b128; B: V' pre-fragmented contiguous)
    f32x4 oacc[4][2] = {};
    #pragma unroll
    for (int ks = 0; ks < 2; ++ks) {
        bf16x8 pa[4], bv[2];
        #pragma unroll
        for (int mi = 0; mi < 4; ++mi)
            pa[mi] = *(const bf16x8*)&P_lds[wave][mi * 16 + c][ks * 32 + hi * 8];
        #pragma unroll
        for (int ni = 0; ni < 2; ++ni)
            bv[ni] = *(const bf16x8*)(vb + ((ks * 4 + hi) * HD + ni * 16 + c) * 8);
        #pragma unroll
        for (int mi = 0; mi < 4; ++mi)
            #pragma unroll
            for (int ni = 0; ni < 2; ++ni)
                oacc[mi][ni] = __builtin_amdgcn_mfma_f32_16x16x32_bf16(
                    pa[mi], bv[ni], oacc[mi][ni], 0, 0, 0);
    }

    // store O rows q<49, scaled by 1/rowsum
    #pragma unroll
    for (int mi = 0; mi < 4; ++mi) {
        #pragma unroll
        for (int r = 0; r < 4; ++r) {
            int q = mi * 16 + hi * 4 + r;
            if (q < L_) {
                size_t rowoff = ((size_t)(win * L_ + q)) * C_ + head * HD;
                float iv = inv_[mi][r];
                #pragma unroll
                for (int ni = 0; ni < 2; ++ni)
                    o_win[rowoff + ni * 16 + c] = f2bf(oacc[mi][ni][r] * iv);
            }
        }
    }
}

// ---------------------------------------------------------------------------
extern "C" void kernel_launch(void* const* d_in, const int* in_sizes, int n_in,
                              void* d_out, int out_size, void* d_ws, size_t ws_size,
                              hipStream_t stream)
{
    (void)in_sizes; (void)n_in; (void)out_size; (void)ws_size;
    const float* x    = (const float*)d_in[0];
    const float* n1g  = (const float*)d_in[3];
    const float* n1b  = (const float*)d_in[4];
    const float* wqkv = (const float*)d_in[5];
    const float* bqkv = (const float*)d_in[6];
    const float* wout = (const float*)d_in[7];
    const float* bout = (const float*)d_in[8];
    const float* n2g  = (const float*)d_in[9];
    const float* n2b  = (const float*)d_in[10];
    const float* w1   = (const float*)d_in[11];
    const float* b1   = (const float*)d_in[12];
    const float* w2   = (const float*)d_in[13];
    const float* b2   = (const float*)d_in[14];
    float* out = (float*)d_out;

    // workspace layout (bf16 shorts)
    unsigned short* bufA_bf = (unsigned short*)d_ws;                 // M*256
    unsigned short* qkv_bf  = bufA_bf + (size_t)M_ * C_;             // 3*NWH*2048 (Q,K,V' planes; aliased by gelu out M*512)
    unsigned short* wqkv_bf = qkv_bf + (size_t)3 * NWH * WHSZ;
    unsigned short* wout_bf = wqkv_bf + 768 * 256;
    unsigned short* w1_bf   = wout_bf + 256 * 256;
    unsigned short* w2_bf   = w1_bf + 512 * 256;

    // 0) weights -> bf16
    cvt_kernel<<<(768 * 256 + 255) / 256, 256, 0, stream>>>(wqkv, wqkv_bf, 768 * 256);
    cvt_kernel<<<(256 * 256 + 255) / 256, 256, 0, stream>>>(wout, wout_bf, 256 * 256);
    cvt_kernel<<<(512 * 256 + 255) / 256, 256, 0, stream>>>(w1, w1_bf, 512 * 256);
    cvt_kernel<<<(256 * 512 + 255) / 256, 256, 0, stream>>>(w2, w2_bf, 256 * 512);

    // 1) LN1 + window partition -> bufA_bf
    ln_kernel<1><<<M_ / 4, 256, 0, stream>>>(x, n1g, n1b, bufA_bf);

    // 2) QKV GEMM -> Q/K/V' planes
    mgemm<0><<<dim3(M_ / GBM, (3 * C_) / GBN), 256, 0, stream>>>(
        bufA_bf, wqkv_bf, bqkv, qkv_bf, nullptr, M_, 3 * C_, C_);

    // 3) MFMA window attention -> o_win (bufA_bf, windowed token x 256)
    mattn<<<NWH / 4, 256, 0, stream>>>(qkv_bf, bufA_bf);

    // 4) out-proj + window merge + residual -> d_out = x1 (f32)
    mgemm<1><<<dim3(M_ / GBM, C_ / GBN), 256, 0, stream>>>(
        bufA_bf, wout_bf, bout, out, x, M_, C_, C_);

    // 5) LN2 -> bufA_bf
    ln_kernel<0><<<M_ / 4, 256, 0, stream>>>(out, n2g, n2b, bufA_bf);

    // 6) MLP fc1 + GELU -> qkv_bf region (M x 512 bf16)
    mgemm<2><<<dim3(M_ / GBM, MLPH / GBN), 256, 0, stream>>>(
        bufA_bf, w1_bf, b1, qkv_bf, nullptr, M_, MLPH, C_);

    // 7) MLP fc2 + residual(x1) -> d_out
    mgemm<3><<<dim3(M_ / GBM, C_ / GBN), 256, 0, stream>>>(
        qkv_bf, w2_bf, b2, out, out, M_, C_, MLPH);
}

// Round 4
// 450.365 us; speedup vs baseline: 3.8001x; 1.0080x over previous
//
#include <hip/hip_runtime.h>
#include <hip/hip_bf16.h>
#include <math.h>

// Problem constants (B=32, H=W=56, C=256, heads=8, hd=32, ws=7)
#define NTOK 3136            // 56*56
#define C_ 256
#define HEADS_ 8
#define HD 32
#define WS_ 7
#define L_ 49
#define NWIN 2048            // 32 * 8 * 8
#define NWH 16384            // NWIN * HEADS_
#define M_ 100352            // NWIN * 49  == BATCH*NTOK
#define MLPH 512
#define WHSZ 2048            // 64 (padded L) * 32 (hd) elems per (win,head) plane

typedef __bf16 bf16x8 __attribute__((ext_vector_type(8)));
typedef float f32x4 __attribute__((ext_vector_type(4)));

__device__ __forceinline__ unsigned short f2bf(float f) {
    union { float f; unsigned u; } v; v.f = f;
    unsigned r = v.u + 0x7fffu + ((v.u >> 16) & 1u);   // RNE
    return (unsigned short)(r >> 16);
}
__device__ __forceinline__ float bf2f(unsigned short s) {
    union { unsigned u; float f; } v; v.u = ((unsigned)s) << 16;
    return v.f;
}

// windowed token index -> natural row index
__device__ __forceinline__ int t2rr(int t) {
    int win = t / L_;
    int l   = t - win * L_;
    int b_  = win >> 6, wh = (win >> 3) & 7, ww = win & 7;
    int ld7 = l / WS_;
    int y   = wh * WS_ + ld7;
    int xc  = ww * WS_ + (l - ld7 * WS_);
    return b_ * NTOK + y * 56 + xc;
}

// ---------------------------------------------------------------------------
__global__ __launch_bounds__(256) void cvt_kernel(
    const float* __restrict__ in, unsigned short* __restrict__ out, int n)
{
    int i = blockIdx.x * 256 + threadIdx.x;
    if (i < n) out[i] = f2bf(in[i]);
}

// ---------------------------------------------------------------------------
// LN1: one wave per token, 4 floats/lane; bf16 output in windowed row order.
// ---------------------------------------------------------------------------
__global__ __launch_bounds__(256) void ln_kernel(
    const float* __restrict__ x, const float* __restrict__ gamma,
    const float* __restrict__ beta, unsigned short* __restrict__ out)
{
    int wave = threadIdx.x >> 6;
    int lane = threadIdx.x & 63;
    int p = blockIdx.x * 4 + wave;
    const float* row = x + (size_t)p * C_;
    float4 v = *(const float4*)(row + lane * 4);
    float s  = v.x + v.y + v.z + v.w;
    float ss = v.x * v.x + v.y * v.y + v.z * v.z + v.w * v.w;
    #pragma unroll
    for (int m = 1; m < 64; m <<= 1) {
        s  += __shfl_xor(s, m, 64);
        ss += __shfl_xor(ss, m, 64);
    }
    float mean = s * (1.0f / C_);
    float var  = ss * (1.0f / C_) - mean * mean;
    float inv  = rsqrtf(var + 1e-5f);
    float4 gv = *(const float4*)(gamma + lane * 4);
    float4 bv = *(const float4*)(beta + lane * 4);
    int b_ = p / NTOK, n = p - b_ * NTOK;
    int y = n / 56, xc = n - y * 56;
    int win = (b_ * 8 + y / WS_) * 8 + xc / WS_;
    int l   = (y % WS_) * WS_ + (xc % WS_);
    size_t orow = (size_t)(win * L_ + l) * C_;
    unsigned short o[4];
    o[0] = f2bf((v.x - mean) * inv * gv.x + bv.x);
    o[1] = f2bf((v.y - mean) * inv * gv.y + bv.y);
    o[2] = f2bf((v.z - mean) * inv * gv.z + bv.z);
    o[3] = f2bf((v.w - mean) * inv * gv.w + bv.w);
    *(uint2*)(out + orow + lane * 4) = *(const uint2*)o;
}

// ---------------------------------------------------------------------------
#define GBM 128
#define GBN 128
#define GBK 32

__device__ __forceinline__ void gload_lds16(const void* g, void* l) {
    __builtin_amdgcn_global_load_lds(
        (const __attribute__((address_space(1))) unsigned*)g,
        (__attribute__((address_space(3))) unsigned*)l, 16, 0, 0);
}

// ---------------------------------------------------------------------------
// mgemm: 128x128 tile, 256 threads. EPI 0: QKV scatter. EPI 2: GELU (fc1).
// ---------------------------------------------------------------------------
template <int EPI>
__global__ __launch_bounds__(256) void mgemm(
    const unsigned short* __restrict__ A, const unsigned short* __restrict__ W,
    const float* __restrict__ bias, void* __restrict__ outv,
    int M, int N, int K)
{
    __shared__ __align__(16) unsigned short As[GBM * GBK];  // 8 KB
    __shared__ __align__(16) unsigned short Bs[GBN * GBK];  // 8 KB

    int tid  = threadIdx.x;
    int w    = tid >> 6;
    int lane = tid & 63;
    int wr = w >> 1, wc = w & 1;
    int bm = blockIdx.x * GBM;
    int bn = blockIdx.y * GBN;
    int srow = lane >> 2;
    int scol = (lane & 3) * 8;
    int c = lane & 15, hi = lane >> 4;

    f32x4 acc[4][4] = {};

    for (int k0 = 0; k0 < K; k0 += GBK) {
        #pragma unroll
        for (int i = 0; i < 2; ++i) {
            int ra = w * 32 + i * 16;
            gload_lds16(A + (size_t)(bm + ra + srow) * K + k0 + scol, &As[ra * GBK]);
            gload_lds16(W + (size_t)(bn + ra + srow) * K + k0 + scol, &Bs[ra * GBK]);
        }
        __syncthreads();

        bf16x8 af[4], bf[4];
        #pragma unroll
        for (int mi = 0; mi < 4; ++mi)
            af[mi] = *(const bf16x8*)&As[(wr * 64 + mi * 16 + c) * GBK + hi * 8];
        #pragma unroll
        for (int ni = 0; ni < 4; ++ni)
            bf[ni] = *(const bf16x8*)&Bs[(wc * 64 + ni * 16 + c) * GBK + hi * 8];

        #pragma unroll
        for (int mi = 0; mi < 4; ++mi)
            #pragma unroll
            for (int ni = 0; ni < 4; ++ni)
                acc[mi][ni] = __builtin_amdgcn_mfma_f32_16x16x32_bf16(
                    af[mi], bf[ni], acc[mi][ni], 0, 0, 0);
        __syncthreads();
    }

    #pragma unroll
    for (int mi = 0; mi < 4; ++mi) {
        #pragma unroll
        for (int r = 0; r < 4; ++r) {
            int row = bm + wr * 64 + mi * 16 + hi * 4 + r;
            int win, l;
            if (EPI == 0) { win = row / L_; l = row - win * L_; }
            #pragma unroll
            for (int ni = 0; ni < 4; ++ni) {
                int col = bn + wc * 64 + ni * 16 + c;
                float val = acc[mi][ni][r] + bias[col];
                if (EPI == 0) {
                    int which = col >> 8;
                    int head  = (col >> 5) & 7;
                    int d     = col & 31;
                    int wh = win * HEADS_ + head;
                    size_t base = (size_t)which * ((size_t)NWH * WHSZ) + (size_t)wh * WHSZ;
                    size_t off;
                    if (which == 2)
                        off = base + (size_t)(((l >> 3) * HD + d) << 3) + (l & 7);
                    else
                        off = base + (size_t)l * HD + d;
                    ((unsigned short*)outv)[off] = f2bf(val);
                } else {
                    float g = 0.5f * val * (1.0f + erff(val * 0.70710678118654752f));
                    ((unsigned short*)outv)[(size_t)row * N + col] = f2bf(g);
                }
            }
        }
    }
}

// ---------------------------------------------------------------------------
// mgemm_ln: out-proj (M x 256 = o_win @ wout^T + bout) fused with residual
// (x gathered windowed) and LN2. 512 threads, block = 128 rows x 256 cols
// (full N). Outputs (both bf16, windowed-sequential): x1 and ln2(x1).
// ---------------------------------------------------------------------------
__global__ __launch_bounds__(512) void mgemm_ln(
    const unsigned short* __restrict__ A, const unsigned short* __restrict__ W,
    const float* __restrict__ bias, const float* __restrict__ x,
    const float* __restrict__ g2, const float* __restrict__ b2,
    unsigned short* __restrict__ x1_out, unsigned short* __restrict__ ln_out)
{
    __shared__ __align__(16) unsigned short As[128 * 32];   // 8 KB
    __shared__ __align__(16) unsigned short Bs[256 * 32];   // 16 KB
    __shared__ __align__(16) unsigned short X1s[128][256];  // 64 KB

    int tid  = threadIdx.x;
    int w    = tid >> 6;          // 0..7
    int lane = tid & 63;
    int wr = w >> 2, wc = w & 3;  // 2 x 4 wave tiles of 64x64
    int bm = blockIdx.x * 128;
    int srow = lane >> 2;
    int scol = (lane & 3) * 8;
    int c = lane & 15, hi = lane >> 4;

    f32x4 acc[4][4] = {};

    for (int k0 = 0; k0 < 256; k0 += 32) {
        gload_lds16(A + (size_t)(bm + w * 16 + srow) * 256 + k0 + scol,
                    &As[(w * 16) * 32]);
        #pragma unroll
        for (int i = 0; i < 2; ++i) {
            int ra = w * 32 + i * 16;
            gload_lds16(W + (size_t)(ra + srow) * 256 + k0 + scol, &Bs[ra * 32]);
        }
        __syncthreads();

        bf16x8 af[4], bf[4];
        #pragma unroll
        for (int mi = 0; mi < 4; ++mi)
            af[mi] = *(const bf16x8*)&As[(wr * 64 + mi * 16 + c) * 32 + hi * 8];
        #pragma unroll
        for (int ni = 0; ni < 4; ++ni)
            bf[ni] = *(const bf16x8*)&Bs[(wc * 64 + ni * 16 + c) * 32 + hi * 8];

        #pragma unroll
        for (int mi = 0; mi < 4; ++mi)
            #pragma unroll
            for (int ni = 0; ni < 4; ++ni)
                acc[mi][ni] = __builtin_amdgcn_mfma_f32_16x16x32_bf16(
                    af[mi], bf[ni], acc[mi][ni], 0, 0, 0);
        __syncthreads();
    }

    // stage o (+bias) to LDS as bf16
    #pragma unroll
    for (int mi = 0; mi < 4; ++mi) {
        #pragma unroll
        for (int ni = 0; ni < 4; ++ni) {
            int colb = wc * 64 + ni * 16 + c;
            float bv = bias[colb];
            #pragma unroll
            for (int r = 0; r < 4; ++r)
                X1s[wr * 64 + mi * 16 + hi * 4 + r][colb] = f2bf(acc[mi][ni][r] + bv);
        }
    }
    __syncthreads();

    // row phase: wave w handles rows [w*16, w*16+16); lane owns 4 cols
    float4 gv = *(const float4*)(g2 + lane * 4);
    float4 bv2 = *(const float4*)(b2 + lane * 4);
    #pragma unroll 2
    for (int i = 0; i < 16; ++i) {
        int tl = w * 16 + i;
        int t = bm + tl;
        int rr = t2rr(t);
        float4 xv = *(const float4*)(x + (size_t)rr * C_ + lane * 4);
        uint2 ov = *(const uint2*)&X1s[tl][lane * 4];
        float x0 = xv.x + bf2f(ov.x & 0xffff);
        float x1 = xv.y + bf2f(ov.x >> 16);
        float x2 = xv.z + bf2f(ov.y & 0xffff);
        float x3 = xv.w + bf2f(ov.y >> 16);
        float s  = x0 + x1 + x2 + x3;
        float ss = x0 * x0 + x1 * x1 + x2 * x2 + x3 * x3;
        #pragma unroll
        for (int m = 1; m < 64; m <<= 1) {
            s  += __shfl_xor(s, m, 64);
            ss += __shfl_xor(ss, m, 64);
        }
        float mean = s * (1.0f / C_);
        float var  = ss * (1.0f / C_) - mean * mean;
        float inv  = rsqrtf(var + 1e-5f);
        uint2 xw, lw;
        xw.x = (unsigned)f2bf(x0) | ((unsigned)f2bf(x1) << 16);
        xw.y = (unsigned)f2bf(x2) | ((unsigned)f2bf(x3) << 16);
        float l0 = (x0 - mean) * inv * gv.x + bv2.x;
        float l1 = (x1 - mean) * inv * gv.y + bv2.y;
        float l2 = (x2 - mean) * inv * gv.z + bv2.z;
        float l3 = (x3 - mean) * inv * gv.w + bv2.w;
        lw.x = (unsigned)f2bf(l0) | ((unsigned)f2bf(l1) << 16);
        lw.y = (unsigned)f2bf(l2) | ((unsigned)f2bf(l3) << 16);
        *(uint2*)(x1_out + (size_t)t * C_ + lane * 4) = xw;
        *(uint2*)(ln_out + (size_t)t * C_ + lane * 4) = lw;
    }
}

// ---------------------------------------------------------------------------
// mgemm_out: fc2 (M x 256 = gelu @ w2^T + b2) + residual (x1 bf16, windowed)
// with LDS-transposed epilogue -> fully coalesced natural-order f32 writes.
// 256 threads, 128x128 tile, K=512.
// ---------------------------------------------------------------------------
__global__ __launch_bounds__(256) void mgemm_out(
    const unsigned short* __restrict__ A, const unsigned short* __restrict__ W,
    const float* __restrict__ bias, const unsigned short* __restrict__ x1,
    float* __restrict__ dout)
{
    __shared__ __align__(16) unsigned short lds_pool[8192];  // 16 KB
    unsigned short* As = lds_pool;
    unsigned short* Bs = lds_pool + 4096;
    float* stage = (float*)lds_pool;                         // 32 x 128 f32

    int tid  = threadIdx.x;
    int w    = tid >> 6;
    int lane = tid & 63;
    int wr = w >> 1, wc = w & 1;
    int bm = blockIdx.x * 128;
    int bn = blockIdx.y * 128;
    int srow = lane >> 2;
    int scol = (lane & 3) * 8;
    int c = lane & 15, hi = lane >> 4;

    f32x4 acc[4][4] = {};

    for (int k0 = 0; k0 < 512; k0 += 32) {
        #pragma unroll
        for (int i = 0; i < 2; ++i) {
            int ra = w * 32 + i * 16;
            gload_lds16(A + (size_t)(bm + ra + srow) * 512 + k0 + scol, &As[ra * 32]);
            gload_lds16(W + (size_t)(bn + ra + srow) * 512 + k0 + scol, &Bs[ra * 32]);
        }
        __syncthreads();

        bf16x8 af[4], bf[4];
        #pragma unroll
        for (int mi = 0; mi < 4; ++mi)
            af[mi] = *(const bf16x8*)&As[(wr * 64 + mi * 16 + c) * 32 + hi * 8];
        #pragma unroll
        for (int ni = 0; ni < 4; ++ni)
            bf[ni] = *(const bf16x8*)&Bs[(wc * 64 + ni * 16 + c) * 32 + hi * 8];

        #pragma unroll
        for (int mi = 0; mi < 4; ++mi)
            #pragma unroll
            for (int ni = 0; ni < 4; ++ni)
                acc[mi][ni] = __builtin_amdgcn_mfma_f32_16x16x32_bf16(
                    af[mi], bf[ni], acc[mi][ni], 0, 0, 0);
        __syncthreads();
    }

    // 4 chunks of 32 rows: stage f32 -> coalesced readback + residual + store
    #pragma unroll
    for (int c2 = 0; c2 < 4; ++c2) {
        if (wr == (c2 >> 1)) {
            int mi0 = (c2 & 1) * 2;
            #pragma unroll
            for (int mm = 0; mm < 2; ++mm) {
                #pragma unroll
                for (int ni = 0; ni < 4; ++ni) {
                    int colb = wc * 64 + ni * 16 + c;
                    float bv = bias[bn + colb];
                    #pragma unroll
                    for (int r = 0; r < 4; ++r)
                        stage[(mm * 16 + hi * 4 + r) * 128 + colb] =
                            acc[mi0 + mm][ni][r] + bv;
                }
            }
        }
        __syncthreads();
        #pragma unroll
        for (int i = 0; i < 4; ++i) {
            int lr = i * 8 + (tid >> 5);         // 0..31
            int t = bm + c2 * 32 + lr;
            int rr = t2rr(t);
            int col4 = (tid & 31) * 4;
            float4 v = *(const float4*)&stage[lr * 128 + col4];
            uint2 rv = *(const uint2*)&x1[(size_t)t * C_ + bn + col4];
            v.x += bf2f(rv.x & 0xffff);
            v.y += bf2f(rv.x >> 16);
            v.z += bf2f(rv.y & 0xffff);
            v.w += bf2f(rv.y >> 16);
            *(float4*)&dout[(size_t)rr * C_ + bn + col4] = v;
        }
        __syncthreads();
    }
}

// ---------------------------------------------------------------------------
// MFMA window attention (unchanged from round 3)
// ---------------------------------------------------------------------------
__global__ __launch_bounds__(256) void mattn(
    const unsigned short* __restrict__ qkv, unsigned short* __restrict__ o_win)
{
    __shared__ __align__(16) unsigned short P_lds[4][64][72];
    int wave = threadIdx.x >> 6, lane = threadIdx.x & 63;
    int c = lane & 15, hi = lane >> 4;
    int wh = blockIdx.x * 4 + wave;
    int win = wh >> 3, head = wh & 7;
    const unsigned short* qb = qkv + (size_t)wh * WHSZ;
    const unsigned short* kb = qb + (size_t)NWH * WHSZ;
    const unsigned short* vb = kb + (size_t)NWH * WHSZ;

    bf16x8 af[4], bk[4];
    #pragma unroll
    for (int mi = 0; mi < 4; ++mi)
        af[mi] = *(const bf16x8*)(qb + (mi * 16 + c) * HD + hi * 8);
    #pragma unroll
    for (int ni = 0; ni < 4; ++ni)
        bk[ni] = *(const bf16x8*)(kb + (ni * 16 + c) * HD + hi * 8);

    f32x4 sacc[4][4] = {};
    #pragma unroll
    for (int mi = 0; mi < 4; ++mi)
        #pragma unroll
        for (int ni = 0; ni < 4; ++ni)
            sacc[mi][ni] = __builtin_amdgcn_mfma_f32_16x16x32_bf16(
                af[mi], bk[ni], sacc[mi][ni], 0, 0, 0);

    const float scale = 0.17677669529663687f;
    float inv_[4][4];
    #pragma unroll
    for (int mi = 0; mi < 4; ++mi) {
        #pragma unroll
        for (int r = 0; r < 4; ++r) {
            float sv[4];
            float m = -1e30f;
            #pragma unroll
            for (int ni = 0; ni < 4; ++ni) {
                float v = sacc[mi][ni][r] * scale;
                v = (ni * 16 + c < L_) ? v : -1e30f;
                sv[ni] = v;
                m = fmaxf(m, v);
            }
            #pragma unroll
            for (int msk = 1; msk < 16; msk <<= 1)
                m = fmaxf(m, __shfl_xor(m, msk, 64));
            float sum = 0.f;
            unsigned short pb[4];
            #pragma unroll
            for (int ni = 0; ni < 4; ++ni) {
                float p = __expf(sv[ni] - m);
                sum += p;
                pb[ni] = f2bf(p);
            }
            #pragma unroll
            for (int msk = 1; msk < 16; msk <<= 1)
                sum += __shfl_xor(sum, msk, 64);
            inv_[mi][r] = 1.0f / sum;
            int q = mi * 16 + hi * 4 + r;
            #pragma unroll
            for (int ni = 0; ni < 4; ++ni)
                P_lds[wave][q][ni * 16 + c] = pb[ni];
        }
    }

    f32x4 oacc[4][2] = {};
    #pragma unroll
    for (int ks = 0; ks < 2; ++ks) {
        bf16x8 pa[4], bv[2];
        #pragma unroll
        for (int mi = 0; mi < 4; ++mi)
            pa[mi] = *(const bf16x8*)&P_lds[wave][mi * 16 + c][ks * 32 + hi * 8];
        #pragma unroll
        for (int ni = 0; ni < 2; ++ni)
            bv[ni] = *(const bf16x8*)(vb + ((ks * 4 + hi) * HD + ni * 16 + c) * 8);
        #pragma unroll
        for (int mi = 0; mi < 4; ++mi)
            #pragma unroll
            for (int ni = 0; ni < 2; ++ni)
                oacc[mi][ni] = __builtin_amdgcn_mfma_f32_16x16x32_bf16(
                    pa[mi], bv[ni], oacc[mi][ni], 0, 0, 0);
    }

    #pragma unroll
    for (int mi = 0; mi < 4; ++mi) {
        #pragma unroll
        for (int r = 0; r < 4; ++r) {
            int q = mi * 16 + hi * 4 + r;
            if (q < L_) {
                size_t rowoff = ((size_t)(win * L_ + q)) * C_ + head * HD;
                float iv = inv_[mi][r];
                #pragma unroll
                for (int ni = 0; ni < 2; ++ni)
                    o_win[rowoff + ni * 16 + c] = f2bf(oacc[mi][ni][r] * iv);
            }
        }
    }
}

// ---------------------------------------------------------------------------
extern "C" void kernel_launch(void* const* d_in, const int* in_sizes, int n_in,
                              void* d_out, int out_size, void* d_ws, size_t ws_size,
                              hipStream_t stream)
{
    (void)in_sizes; (void)n_in; (void)out_size; (void)ws_size;
    const float* x    = (const float*)d_in[0];
    const float* n1g  = (const float*)d_in[3];
    const float* n1b  = (const float*)d_in[4];
    const float* wqkv = (const float*)d_in[5];
    const float* bqkv = (const float*)d_in[6];
    const float* wout = (const float*)d_in[7];
    const float* bout = (const float*)d_in[8];
    const float* n2g  = (const float*)d_in[9];
    const float* n2b  = (const float*)d_in[10];
    const float* w1   = (const float*)d_in[11];
    const float* b1   = (const float*)d_in[12];
    const float* w2   = (const float*)d_in[13];
    const float* b2   = (const float*)d_in[14];
    float* out = (float*)d_out;

    // workspace layout (bf16 shorts)
    unsigned short* bufA_bf = (unsigned short*)d_ws;                 // M*256 (LN1 out, then o_win)
    unsigned short* qkv_bf  = bufA_bf + (size_t)M_ * C_;             // 3*NWH*2048 (Q,K,V'; later gelu M*512)
    unsigned short* x1_bf   = qkv_bf + (size_t)3 * NWH * WHSZ;       // M*256
    unsigned short* ln2_bf  = x1_bf + (size_t)M_ * C_;               // M*256
    unsigned short* wqkv_bf = ln2_bf + (size_t)M_ * C_;
    unsigned short* wout_bf = wqkv_bf + 768 * 256;
    unsigned short* w1_bf   = wout_bf + 256 * 256;
    unsigned short* w2_bf   = w1_bf + 512 * 256;

    // 0) weights -> bf16
    cvt_kernel<<<(768 * 256 + 255) / 256, 256, 0, stream>>>(wqkv, wqkv_bf, 768 * 256);
    cvt_kernel<<<(256 * 256 + 255) / 256, 256, 0, stream>>>(wout, wout_bf, 256 * 256);
    cvt_kernel<<<(512 * 256 + 255) / 256, 256, 0, stream>>>(w1, w1_bf, 512 * 256);
    cvt_kernel<<<(256 * 512 + 255) / 256, 256, 0, stream>>>(w2, w2_bf, 256 * 512);

    // 1) LN1 + window partition -> bufA_bf
    ln_kernel<<<M_ / 4, 256, 0, stream>>>(x, n1g, n1b, bufA_bf);

    // 2) QKV GEMM -> Q/K/V' planes
    mgemm<0><<<dim3(M_ / GBM, (3 * C_) / GBN), 256, 0, stream>>>(
        bufA_bf, wqkv_bf, bqkv, qkv_bf, M_, 3 * C_, C_);

    // 3) MFMA window attention -> o_win (bufA_bf)
    mattn<<<NWH / 4, 256, 0, stream>>>(qkv_bf, bufA_bf);

    // 4) out-proj + residual + LN2 fused -> x1_bf, ln2_bf (both windowed)
    mgemm_ln<<<M_ / 128, 512, 0, stream>>>(
        bufA_bf, wout_bf, bout, x, n2g, n2b, x1_bf, ln2_bf);

    // 5) MLP fc1 + GELU -> qkv_bf region (M x 512 bf16)
    mgemm<2><<<dim3(M_ / GBM, MLPH / GBN), 256, 0, stream>>>(
        ln2_bf, w1_bf, b1, qkv_bf, M_, MLPH, C_);

    // 6) MLP fc2 + residual(x1_bf) -> d_out (natural order, coalesced)
    mgemm_out<<<dim3(M_ / 128, C_ / 128), 256, 0, stream>>>(
        qkv_bf, w2_bf, b2, x1_bf, out);
}

// Round 5
// 423.359 us; speedup vs baseline: 4.0425x; 1.0638x over previous
//
#include <hip/hip_runtime.h>
#include <hip/hip_bf16.h>
#include <math.h>

// Problem constants (B=32, H=W=56, C=256, heads=8, hd=32, ws=7)
#define NTOK 3136            // 56*56
#define C_ 256
#define HEADS_ 8
#define HD 32
#define WS_ 7
#define L_ 49
#define NWIN 2048            // 32 * 8 * 8
#define NWH 16384            // NWIN * HEADS_
#define M_ 100352            // NWIN * 49  == BATCH*NTOK
#define MLPH 512
#define WHSZ 2048            // 64 (padded L) * 32 (hd) elems per (win,head) plane

typedef __bf16 bf16x8 __attribute__((ext_vector_type(8)));
typedef float f32x4 __attribute__((ext_vector_type(4)));

__device__ __forceinline__ unsigned short f2bf(float f) {
    union { float f; unsigned u; } v; v.f = f;
    unsigned r = v.u + 0x7fffu + ((v.u >> 16) & 1u);   // RNE
    return (unsigned short)(r >> 16);
}
__device__ __forceinline__ float bf2f(unsigned short s) {
    union { unsigned u; float f; } v; v.u = ((unsigned)s) << 16;
    return v.f;
}

// windowed token index -> natural row index
__device__ __forceinline__ int t2rr(int t) {
    int win = t / L_;
    int l   = t - win * L_;
    int b_  = win >> 6, wh = (win >> 3) & 7, ww = win & 7;
    int ld7 = l / WS_;
    int y   = wh * WS_ + ld7;
    int xc  = ww * WS_ + (l - ld7 * WS_);
    return b_ * NTOK + y * 56 + xc;
}

// XCD-chunked bm-major remap: all bn-tiles of a bm-chunk stay on one XCD so
// the A stripe is fetched from HBM once (L2-resident for the chunk).
template <int NBN>
__device__ __forceinline__ void xcd_decode(int nb, int& bm, int& bn) {
    int h = blockIdx.x;
    int fid = (h & 7) * (nb >> 3) + (h >> 3);
    int bmi = fid / NBN;
    bm = bmi * 128;
    bn = (fid - bmi * NBN) * 128;
}

// ---------------------------------------------------------------------------
__global__ __launch_bounds__(256) void cvt_kernel(
    const float* __restrict__ in, unsigned short* __restrict__ out, int n)
{
    int i = blockIdx.x * 256 + threadIdx.x;
    if (i < n) out[i] = f2bf(in[i]);
}

// ---------------------------------------------------------------------------
// LN1: one wave per token, 4 floats/lane; bf16 output in windowed row order.
// ---------------------------------------------------------------------------
__global__ __launch_bounds__(256) void ln_kernel(
    const float* __restrict__ x, const float* __restrict__ gamma,
    const float* __restrict__ beta, unsigned short* __restrict__ out)
{
    int wave = threadIdx.x >> 6;
    int lane = threadIdx.x & 63;
    int p = blockIdx.x * 4 + wave;
    const float* row = x + (size_t)p * C_;
    float4 v = *(const float4*)(row + lane * 4);
    float s  = v.x + v.y + v.z + v.w;
    float ss = v.x * v.x + v.y * v.y + v.z * v.z + v.w * v.w;
    #pragma unroll
    for (int m = 1; m < 64; m <<= 1) {
        s  += __shfl_xor(s, m, 64);
        ss += __shfl_xor(ss, m, 64);
    }
    float mean = s * (1.0f / C_);
    float var  = ss * (1.0f / C_) - mean * mean;
    float inv  = rsqrtf(var + 1e-5f);
    float4 gv = *(const float4*)(gamma + lane * 4);
    float4 bv = *(const float4*)(beta + lane * 4);
    int b_ = p / NTOK, n = p - b_ * NTOK;
    int y = n / 56, xc = n - y * 56;
    int win = (b_ * 8 + y / WS_) * 8 + xc / WS_;
    int l   = (y % WS_) * WS_ + (xc % WS_);
    size_t orow = (size_t)(win * L_ + l) * C_;
    unsigned short o[4];
    o[0] = f2bf((v.x - mean) * inv * gv.x + bv.x);
    o[1] = f2bf((v.y - mean) * inv * gv.y + bv.y);
    o[2] = f2bf((v.z - mean) * inv * gv.z + bv.z);
    o[3] = f2bf((v.w - mean) * inv * gv.w + bv.w);
    *(uint2*)(out + orow + lane * 4) = *(const uint2*)o;
}

// ---------------------------------------------------------------------------
#define GBM 128
#define GBN 128
#define GBK 32

__device__ __forceinline__ void gload_lds16(const void* g, void* l) {
    __builtin_amdgcn_global_load_lds(
        (const __attribute__((address_space(1))) unsigned*)g,
        (__attribute__((address_space(3))) unsigned*)l, 16, 0, 0);
}

// ---------------------------------------------------------------------------
// mgemm: 128x128 tile, 256 threads. EPI 0: QKV scatter. EPI 2: GELU (fc1).
// NBN = column tiles (for XCD-chunked remap).
// ---------------------------------------------------------------------------
template <int EPI, int NBN>
__global__ __launch_bounds__(256) void mgemm(
    const unsigned short* __restrict__ A, const unsigned short* __restrict__ W,
    const float* __restrict__ bias, void* __restrict__ outv,
    int M, int N, int K)
{
    __shared__ __align__(16) unsigned short As[GBM * GBK];  // 8 KB
    __shared__ __align__(16) unsigned short Bs[GBN * GBK];  // 8 KB

    int tid  = threadIdx.x;
    int w    = tid >> 6;
    int lane = tid & 63;
    int wr = w >> 1, wc = w & 1;
    int bm, bn;
    xcd_decode<NBN>(gridDim.x, bm, bn);
    int srow = lane >> 2;
    int scol = (lane & 3) * 8;
    int c = lane & 15, hi = lane >> 4;

    f32x4 acc[4][4] = {};

    for (int k0 = 0; k0 < K; k0 += GBK) {
        #pragma unroll
        for (int i = 0; i < 2; ++i) {
            int ra = w * 32 + i * 16;
            gload_lds16(A + (size_t)(bm + ra + srow) * K + k0 + scol, &As[ra * GBK]);
            gload_lds16(W + (size_t)(bn + ra + srow) * K + k0 + scol, &Bs[ra * GBK]);
        }
        __syncthreads();

        bf16x8 af[4], bf[4];
        #pragma unroll
        for (int mi = 0; mi < 4; ++mi)
            af[mi] = *(const bf16x8*)&As[(wr * 64 + mi * 16 + c) * GBK + hi * 8];
        #pragma unroll
        for (int ni = 0; ni < 4; ++ni)
            bf[ni] = *(const bf16x8*)&Bs[(wc * 64 + ni * 16 + c) * GBK + hi * 8];

        #pragma unroll
        for (int mi = 0; mi < 4; ++mi)
            #pragma unroll
            for (int ni = 0; ni < 4; ++ni)
                acc[mi][ni] = __builtin_amdgcn_mfma_f32_16x16x32_bf16(
                    af[mi], bf[ni], acc[mi][ni], 0, 0, 0);
        __syncthreads();
    }

    #pragma unroll
    for (int mi = 0; mi < 4; ++mi) {
        #pragma unroll
        for (int r = 0; r < 4; ++r) {
            int row = bm + wr * 64 + mi * 16 + hi * 4 + r;
            int win, l;
            if (EPI == 0) { win = row / L_; l = row - win * L_; }
            #pragma unroll
            for (int ni = 0; ni < 4; ++ni) {
                int col = bn + wc * 64 + ni * 16 + c;
                float val = acc[mi][ni][r] + bias[col];
                if (EPI == 0) {
                    int which = col >> 8;
                    int head  = (col >> 5) & 7;
                    int d     = col & 31;
                    int wh = win * HEADS_ + head;
                    size_t base = (size_t)which * ((size_t)NWH * WHSZ) + (size_t)wh * WHSZ;
                    size_t off;
                    if (which == 2)
                        off = base + (size_t)(((l >> 3) * HD + d) << 3) + (l & 7);
                    else
                        off = base + (size_t)l * HD + d;
                    ((unsigned short*)outv)[off] = f2bf(val);
                } else {
                    float g = 0.5f * val * (1.0f + erff(val * 0.70710678118654752f));
                    ((unsigned short*)outv)[(size_t)row * N + col] = f2bf(g);
                }
            }
        }
    }
}

// ---------------------------------------------------------------------------
// mgemm_ln: out-proj (M x 256 = o_win @ wout^T + bout) fused with residual
// (x gathered windowed) and LN2. 512 threads, block = 128 rows x 256 cols
// (full N). Outputs (both bf16, windowed-sequential): x1 and ln2(x1).
// ---------------------------------------------------------------------------
__global__ __launch_bounds__(512) void mgemm_ln(
    const unsigned short* __restrict__ A, const unsigned short* __restrict__ W,
    const float* __restrict__ bias, const float* __restrict__ x,
    const float* __restrict__ g2, const float* __restrict__ b2,
    unsigned short* __restrict__ x1_out, unsigned short* __restrict__ ln_out)
{
    __shared__ __align__(16) unsigned short As[128 * 32];   // 8 KB
    __shared__ __align__(16) unsigned short Bs[256 * 32];   // 16 KB
    __shared__ __align__(16) unsigned short X1s[128][256];  // 64 KB

    int tid  = threadIdx.x;
    int w    = tid >> 6;          // 0..7
    int lane = tid & 63;
    int wr = w >> 2, wc = w & 3;  // 2 x 4 wave tiles of 64x64
    int bm = blockIdx.x * 128;
    int srow = lane >> 2;
    int scol = (lane & 3) * 8;
    int c = lane & 15, hi = lane >> 4;

    f32x4 acc[4][4] = {};

    for (int k0 = 0; k0 < 256; k0 += 32) {
        gload_lds16(A + (size_t)(bm + w * 16 + srow) * 256 + k0 + scol,
                    &As[(w * 16) * 32]);
        #pragma unroll
        for (int i = 0; i < 2; ++i) {
            int ra = w * 32 + i * 16;
            gload_lds16(W + (size_t)(ra + srow) * 256 + k0 + scol, &Bs[ra * 32]);
        }
        __syncthreads();

        bf16x8 af[4], bf[4];
        #pragma unroll
        for (int mi = 0; mi < 4; ++mi)
            af[mi] = *(const bf16x8*)&As[(wr * 64 + mi * 16 + c) * 32 + hi * 8];
        #pragma unroll
        for (int ni = 0; ni < 4; ++ni)
            bf[ni] = *(const bf16x8*)&Bs[(wc * 64 + ni * 16 + c) * 32 + hi * 8];

        #pragma unroll
        for (int mi = 0; mi < 4; ++mi)
            #pragma unroll
            for (int ni = 0; ni < 4; ++ni)
                acc[mi][ni] = __builtin_amdgcn_mfma_f32_16x16x32_bf16(
                    af[mi], bf[ni], acc[mi][ni], 0, 0, 0);
        __syncthreads();
    }

    // stage o (+bias) to LDS as bf16
    #pragma unroll
    for (int mi = 0; mi < 4; ++mi) {
        #pragma unroll
        for (int ni = 0; ni < 4; ++ni) {
            int colb = wc * 64 + ni * 16 + c;
            float bv = bias[colb];
            #pragma unroll
            for (int r = 0; r < 4; ++r)
                X1s[wr * 64 + mi * 16 + hi * 4 + r][colb] = f2bf(acc[mi][ni][r] + bv);
        }
    }
    __syncthreads();

    // row phase: wave w handles rows [w*16, w*16+16); lane owns 4 cols
    float4 gv = *(const float4*)(g2 + lane * 4);
    float4 bv2 = *(const float4*)(b2 + lane * 4);
    #pragma unroll 2
    for (int i = 0; i < 16; ++i) {
        int tl = w * 16 + i;
        int t = bm + tl;
        int rr = t2rr(t);
        float4 xv = *(const float4*)(x + (size_t)rr * C_ + lane * 4);
        uint2 ov = *(const uint2*)&X1s[tl][lane * 4];
        float x0 = xv.x + bf2f(ov.x & 0xffff);
        float x1 = xv.y + bf2f(ov.x >> 16);
        float x2 = xv.z + bf2f(ov.y & 0xffff);
        float x3 = xv.w + bf2f(ov.y >> 16);
        float s  = x0 + x1 + x2 + x3;
        float ss = x0 * x0 + x1 * x1 + x2 * x2 + x3 * x3;
        #pragma unroll
        for (int m = 1; m < 64; m <<= 1) {
            s  += __shfl_xor(s, m, 64);
            ss += __shfl_xor(ss, m, 64);
        }
        float mean = s * (1.0f / C_);
        float var  = ss * (1.0f / C_) - mean * mean;
        float inv  = rsqrtf(var + 1e-5f);
        uint2 xw, lw;
        xw.x = (unsigned)f2bf(x0) | ((unsigned)f2bf(x1) << 16);
        xw.y = (unsigned)f2bf(x2) | ((unsigned)f2bf(x3) << 16);
        float l0 = (x0 - mean) * inv * gv.x + bv2.x;
        float l1 = (x1 - mean) * inv * gv.y + bv2.y;
        float l2 = (x2 - mean) * inv * gv.z + bv2.z;
        float l3 = (x3 - mean) * inv * gv.w + bv2.w;
        lw.x = (unsigned)f2bf(l0) | ((unsigned)f2bf(l1) << 16);
        lw.y = (unsigned)f2bf(l2) | ((unsigned)f2bf(l3) << 16);
        *(uint2*)(x1_out + (size_t)t * C_ + lane * 4) = xw;
        *(uint2*)(ln_out + (size_t)t * C_ + lane * 4) = lw;
    }
}

// ---------------------------------------------------------------------------
// mgemm_out: fc2 (M x 256 = gelu @ w2^T + b2) + residual (x1 bf16, windowed)
// with LDS-transposed epilogue -> fully coalesced natural-order f32 writes.
// 256 threads, 128x128 tile, K=512, XCD-chunked remap (NBN=2).
// ---------------------------------------------------------------------------
__global__ __launch_bounds__(256) void mgemm_out(
    const unsigned short* __restrict__ A, const unsigned short* __restrict__ W,
    const float* __restrict__ bias, const unsigned short* __restrict__ x1,
    float* __restrict__ dout)
{
    __shared__ __align__(16) unsigned short lds_pool[8192];  // 16 KB
    unsigned short* As = lds_pool;
    unsigned short* Bs = lds_pool + 4096;
    float* stage = (float*)lds_pool;                         // 32 x 128 f32

    int tid  = threadIdx.x;
    int w    = tid >> 6;
    int lane = tid & 63;
    int wr = w >> 1, wc = w & 1;
    int bm, bn;
    xcd_decode<2>(gridDim.x, bm, bn);
    int srow = lane >> 2;
    int scol = (lane & 3) * 8;
    int c = lane & 15, hi = lane >> 4;

    f32x4 acc[4][4] = {};

    for (int k0 = 0; k0 < 512; k0 += 32) {
        #pragma unroll
        for (int i = 0; i < 2; ++i) {
            int ra = w * 32 + i * 16;
            gload_lds16(A + (size_t)(bm + ra + srow) * 512 + k0 + scol, &As[ra * 32]);
            gload_lds16(W + (size_t)(bn + ra + srow) * 512 + k0 + scol, &Bs[ra * 32]);
        }
        __syncthreads();

        bf16x8 af[4], bf[4];
        #pragma unroll
        for (int mi = 0; mi < 4; ++mi)
            af[mi] = *(const bf16x8*)&As[(wr * 64 + mi * 16 + c) * 32 + hi * 8];
        #pragma unroll
        for (int ni = 0; ni < 4; ++ni)
            bf[ni] = *(const bf16x8*)&Bs[(wc * 64 + ni * 16 + c) * 32 + hi * 8];

        #pragma unroll
        for (int mi = 0; mi < 4; ++mi)
            #pragma unroll
            for (int ni = 0; ni < 4; ++ni)
                acc[mi][ni] = __builtin_amdgcn_mfma_f32_16x16x32_bf16(
                    af[mi], bf[ni], acc[mi][ni], 0, 0, 0);
        __syncthreads();
    }

    // 4 chunks of 32 rows: stage f32 -> coalesced readback + residual + store
    #pragma unroll
    for (int c2 = 0; c2 < 4; ++c2) {
        if (wr == (c2 >> 1)) {
            int mi0 = (c2 & 1) * 2;
            #pragma unroll
            for (int mm = 0; mm < 2; ++mm) {
                #pragma unroll
                for (int ni = 0; ni < 4; ++ni) {
                    int colb = wc * 64 + ni * 16 + c;
                    float bv = bias[bn + colb];
                    #pragma unroll
                    for (int r = 0; r < 4; ++r)
                        stage[(mm * 16 + hi * 4 + r) * 128 + colb] =
                            acc[mi0 + mm][ni][r] + bv;
                }
            }
        }
        __syncthreads();
        #pragma unroll
        for (int i = 0; i < 4; ++i) {
            int lr = i * 8 + (tid >> 5);         // 0..31
            int t = bm + c2 * 32 + lr;
            int rr = t2rr(t);
            int col4 = (tid & 31) * 4;
            float4 v = *(const float4*)&stage[lr * 128 + col4];
            uint2 rv = *(const uint2*)&x1[(size_t)t * C_ + bn + col4];
            v.x += bf2f(rv.x & 0xffff);
            v.y += bf2f(rv.x >> 16);
            v.z += bf2f(rv.y & 0xffff);
            v.w += bf2f(rv.y >> 16);
            *(float4*)&dout[(size_t)rr * C_ + bn + col4] = v;
        }
        __syncthreads();
    }
}

// ---------------------------------------------------------------------------
// MFMA window attention (unchanged)
// ---------------------------------------------------------------------------
__global__ __launch_bounds__(256) void mattn(
    const unsigned short* __restrict__ qkv, unsigned short* __restrict__ o_win)
{
    __shared__ __align__(16) unsigned short P_lds[4][64][72];
    int wave = threadIdx.x >> 6, lane = threadIdx.x & 63;
    int c = lane & 15, hi = lane >> 4;
    int wh = blockIdx.x * 4 + wave;
    int win = wh >> 3, head = wh & 7;
    const unsigned short* qb = qkv + (size_t)wh * WHSZ;
    const unsigned short* kb = qb + (size_t)NWH * WHSZ;
    const unsigned short* vb = kb + (size_t)NWH * WHSZ;

    bf16x8 af[4], bk[4];
    #pragma unroll
    for (int mi = 0; mi < 4; ++mi)
        af[mi] = *(const bf16x8*)(qb + (mi * 16 + c) * HD + hi * 8);
    #pragma unroll
    for (int ni = 0; ni < 4; ++ni)
        bk[ni] = *(const bf16x8*)(kb + (ni * 16 + c) * HD + hi * 8);

    f32x4 sacc[4][4] = {};
    #pragma unroll
    for (int mi = 0; mi < 4; ++mi)
        #pragma unroll
        for (int ni = 0; ni < 4; ++ni)
            sacc[mi][ni] = __builtin_amdgcn_mfma_f32_16x16x32_bf16(
                af[mi], bk[ni], sacc[mi][ni], 0, 0, 0);

    const float scale = 0.17677669529663687f;
    float inv_[4][4];
    #pragma unroll
    for (int mi = 0; mi < 4; ++mi) {
        #pragma unroll
        for (int r = 0; r < 4; ++r) {
            float sv[4];
            float m = -1e30f;
            #pragma unroll
            for (int ni = 0; ni < 4; ++ni) {
                float v = sacc[mi][ni][r] * scale;
                v = (ni * 16 + c < L_) ? v : -1e30f;
                sv[ni] = v;
                m = fmaxf(m, v);
            }
            #pragma unroll
            for (int msk = 1; msk < 16; msk <<= 1)
                m = fmaxf(m, __shfl_xor(m, msk, 64));
            float sum = 0.f;
            unsigned short pb[4];
            #pragma unroll
            for (int ni = 0; ni < 4; ++ni) {
                float p = __expf(sv[ni] - m);
                sum += p;
                pb[ni] = f2bf(p);
            }
            #pragma unroll
            for (int msk = 1; msk < 16; msk <<= 1)
                sum += __shfl_xor(sum, msk, 64);
            inv_[mi][r] = 1.0f / sum;
            int q = mi * 16 + hi * 4 + r;
            #pragma unroll
            for (int ni = 0; ni < 4; ++ni)
                P_lds[wave][q][ni * 16 + c] = pb[ni];
        }
    }

    f32x4 oacc[4][2] = {};
    #pragma unroll
    for (int ks = 0; ks < 2; ++ks) {
        bf16x8 pa[4], bv[2];
        #pragma unroll
        for (int mi = 0; mi < 4; ++mi)
            pa[mi] = *(const bf16x8*)&P_lds[wave][mi * 16 + c][ks * 32 + hi * 8];
        #pragma unroll
        for (int ni = 0; ni < 2; ++ni)
            bv[ni] = *(const bf16x8*)(vb + ((ks * 4 + hi) * HD + ni * 16 + c) * 8);
        #pragma unroll
        for (int mi = 0; mi < 4; ++mi)
            #pragma unroll
            for (int ni = 0; ni < 2; ++ni)
                oacc[mi][ni] = __builtin_amdgcn_mfma_f32_16x16x32_bf16(
                    pa[mi], bv[ni], oacc[mi][ni], 0, 0, 0);
    }

    #pragma unroll
    for (int mi = 0; mi < 4; ++mi) {
        #pragma unroll
        for (int r = 0; r < 4; ++r) {
            int q = mi * 16 + hi * 4 + r;
            if (q < L_) {
                size_t rowoff = ((size_t)(win * L_ + q)) * C_ + head * HD;
                float iv = inv_[mi][r];
                #pragma unroll
                for (int ni = 0; ni < 2; ++ni)
                    o_win[rowoff + ni * 16 + c] = f2bf(oacc[mi][ni][r] * iv);
            }
        }
    }
}

// ---------------------------------------------------------------------------
extern "C" void kernel_launch(void* const* d_in, const int* in_sizes, int n_in,
                              void* d_out, int out_size, void* d_ws, size_t ws_size,
                              hipStream_t stream)
{
    (void)in_sizes; (void)n_in; (void)out_size; (void)ws_size;
    const float* x    = (const float*)d_in[0];
    const float* n1g  = (const float*)d_in[3];
    const float* n1b  = (const float*)d_in[4];
    const float* wqkv = (const float*)d_in[5];
    const float* bqkv = (const float*)d_in[6];
    const float* wout = (const float*)d_in[7];
    const float* bout = (const float*)d_in[8];
    const float* n2g  = (const float*)d_in[9];
    const float* n2b  = (const float*)d_in[10];
    const float* w1   = (const float*)d_in[11];
    const float* b1   = (const float*)d_in[12];
    const float* w2   = (const float*)d_in[13];
    const float* b2   = (const float*)d_in[14];
    float* out = (float*)d_out;

    // workspace layout (bf16 shorts)
    unsigned short* bufA_bf = (unsigned short*)d_ws;                 // M*256 (LN1 out, then o_win)
    unsigned short* qkv_bf  = bufA_bf + (size_t)M_ * C_;             // 3*NWH*2048 (Q,K,V'; later gelu M*512)
    unsigned short* x1_bf   = qkv_bf + (size_t)3 * NWH * WHSZ;       // M*256
    unsigned short* ln2_bf  = x1_bf + (size_t)M_ * C_;               // M*256
    unsigned short* wqkv_bf = ln2_bf + (size_t)M_ * C_;
    unsigned short* wout_bf = wqkv_bf + 768 * 256;
    unsigned short* w1_bf   = wout_bf + 256 * 256;
    unsigned short* w2_bf   = w1_bf + 512 * 256;

    // 0) weights -> bf16
    cvt_kernel<<<(768 * 256 + 255) / 256, 256, 0, stream>>>(wqkv, wqkv_bf, 768 * 256);
    cvt_kernel<<<(256 * 256 + 255) / 256, 256, 0, stream>>>(wout, wout_bf, 256 * 256);
    cvt_kernel<<<(512 * 256 + 255) / 256, 256, 0, stream>>>(w1, w1_bf, 512 * 256);
    cvt_kernel<<<(256 * 512 + 255) / 256, 256, 0, stream>>>(w2, w2_bf, 256 * 512);

    // 1) LN1 + window partition -> bufA_bf
    ln_kernel<<<M_ / 4, 256, 0, stream>>>(x, n1g, n1b, bufA_bf);

    // 2) QKV GEMM -> Q/K/V' planes  (XCD-chunked, 784*6 blocks)
    mgemm<0, 6><<<(M_ / GBM) * 6, 256, 0, stream>>>(
        bufA_bf, wqkv_bf, bqkv, qkv_bf, M_, 3 * C_, C_);

    // 3) MFMA window attention -> o_win (bufA_bf)
    mattn<<<NWH / 4, 256, 0, stream>>>(qkv_bf, bufA_bf);

    // 4) out-proj + residual + LN2 fused -> x1_bf, ln2_bf (both windowed)
    mgemm_ln<<<M_ / 128, 512, 0, stream>>>(
        bufA_bf, wout_bf, bout, x, n2g, n2b, x1_bf, ln2_bf);

    // 5) MLP fc1 + GELU -> qkv_bf region  (XCD-chunked, 784*4 blocks)
    mgemm<2, 4><<<(M_ / GBM) * 4, 256, 0, stream>>>(
        ln2_bf, w1_bf, b1, qkv_bf, M_, MLPH, C_);

    // 6) MLP fc2 + residual(x1_bf) -> d_out  (XCD-chunked, 784*2 blocks)
    mgemm_out<<<(M_ / 128) * 2, 256, 0, stream>>>(
        qkv_bf, w2_bf, b2, x1_bf, out);
}